// Round 7
// baseline (276.493 us; speedup 1.0000x reference)
//
#include <hip/hip_runtime.h>

// Problem constants: B=16, S=2048, D=1024, P=8192, R=16, NL=64, span<=31
#define S_LEN      2048
#define D_DIM      1024
#define R_DIM      16
#define OUT_STRIDE 2064          // 2*D + R
#define NKEYS      32768         // B * S_LEN flat row keys
#define GROUP      8             // sorted jobs per gather group
#define SEG        64            // rows per LDS weight-table segment

// ---------------------------------------------------------------------------
// Counting sort of the 2P span-jobs by flat start row (b*S + s).
// ws layout: [0,128KB) int cursor[NKEYS]; [128KB,192KB) int sorted[2P]

__global__ __launch_bounds__(256) void zero_hist(int* __restrict__ h) {
    h[blockIdx.x * 256 + threadIdx.x] = 0;
}

__global__ __launch_bounds__(256) void hist_jobs(
    const int* __restrict__ bidx, const int* __restrict__ e1s,
    const int* __restrict__ e2s, int* __restrict__ hist, int njobs)
{
    const int j = blockIdx.x * 256 + threadIdx.x;
    if (j >= njobs) return;
    const int p = j >> 1;
    const int s = (j & 1) ? e2s[p] : e1s[p];
    atomicAdd(hist + bidx[p] * S_LEN + s, 1);
}

// single block, 1024 threads, 32 keys/thread: exclusive scan of NKEYS counts
__global__ __launch_bounds__(1024) void scan_hist(int* __restrict__ hist) {
    __shared__ int lds[1024];
    const int t = threadIdx.x;
    int v[32];
    int sum = 0;
#pragma unroll
    for (int i = 0; i < 32; ++i) { v[i] = hist[t * 32 + i]; sum += v[i]; }
    lds[t] = sum;
    __syncthreads();
    for (int off = 1; off < 1024; off <<= 1) {   // Hillis-Steele inclusive
        int x = (t >= off) ? lds[t - off] : 0;
        __syncthreads();
        lds[t] += x;
        __syncthreads();
    }
    int run = (t == 0) ? 0 : lds[t - 1];
#pragma unroll
    for (int i = 0; i < 32; ++i) { int c = v[i]; hist[t * 32 + i] = run; run += c; }
}

__global__ __launch_bounds__(256) void scatter_jobs(
    const int* __restrict__ bidx, const int* __restrict__ e1s,
    const int* __restrict__ e2s, int* __restrict__ cursor,
    int* __restrict__ sorted, int njobs)
{
    const int j = blockIdx.x * 256 + threadIdx.x;
    if (j >= njobs) return;
    const int p = j >> 1;
    const int s = (j & 1) ? e2s[p] : e1s[p];
    const int pos = atomicAdd(cursor + bidx[p] * S_LEN + s, 1);
    sorted[pos] = j;
}

// ---------------------------------------------------------------------------
// Grouped gather v4: LDS weight table -> ZERO scalar ops in the hot loop.
// R4/R5/R6 were scalar-ALU-bound: wave-uniform weight selects compile to SALU
// cselect chains, and the SALU is ONE shared pipe per CU — saturating it made
// throughput occupancy-invariant (R6's finding). Here weights for a 64-row
// segment are precomputed into LDS once; the per-row body is 1 global float4
// load + 2 ds_read_b128 broadcasts + 32 v_fma — the R3 shape (~7 TB/s).
__global__ __launch_bounds__(128) void gather_grouped4(
    const float* __restrict__ tok,     // [B*S, D] fp32
    const int*   __restrict__ sorted,  // [2P] sorted job ids
    const int*   __restrict__ bidx,
    const int*   __restrict__ e1s, const int* __restrict__ e1e,
    const int*   __restrict__ e2s, const int* __restrict__ e2e,
    const int*   __restrict__ ridx,
    const float* __restrict__ rtab,    // [NL, R]
    float*       __restrict__ out)     // [P, 2D+R]
{
    __shared__ int   jsL[GROUP], jeL[GROUP];
    __shared__ float jwL[GROUP];
    __shared__ float wtab[SEG][GROUP];     // 2KB weight table per segment

    const int blk = blockIdx.x;
    // XCD swizzle: contiguous sorted range per XCD for L2 locality
    const int w  = (blk & 7) * (gridDim.x >> 3) + (blk >> 3);
    const int g  = w >> 1;            // job group (8 sorted jobs)
    const int ch = w & 1;             // column half: cols [ch*512, ch*512+512)
    const int t  = threadIdx.x;       // 128 threads x 4 cols = 512 cols

    int   jp[GROUP], jh[GROUP];
    int mins = 0x7fffffff, maxe = 0;
#pragma unroll
    for (int i = 0; i < GROUP; ++i) {
        const int id = __builtin_amdgcn_readfirstlane(sorted[g * GROUP + i]);
        const int p  = id >> 1;
        const int h  = id & 1;
        const int b  = __builtin_amdgcn_readfirstlane(bidx[p]);
        const int s  = __builtin_amdgcn_readfirstlane(h ? e2s[p] : e1s[p]);
        const int e  = __builtin_amdgcn_readfirstlane(h ? e2e[p] : e1e[p]);
        jp[i] = p; jh[i] = h;
        const int fs = b * S_LEN + s;
        const int fe = b * S_LEN + e;
        if (t == i) { jsL[i] = fs; jeL[i] = fe; jwL[i] = 1.0f / (float)(e - s); }
        mins = min(mins, fs);
        maxe = max(maxe, fe);
    }

    float4 acc[GROUP];
#pragma unroll
    for (int i = 0; i < GROUP; ++i) acc[i] = make_float4(0.f, 0.f, 0.f, 0.f);

    // row stride = D/4 = 256 float4; this block's slice starts at ch*128 + t
    const float4* base = reinterpret_cast<const float4*>(tok) +
                         (size_t)mins * (D_DIM / 4) + ch * 128 + t;
    const int nrows = maxe - mins;

    for (int seg0 = 0; seg0 < nrows; seg0 += SEG) {
        __syncthreads();
        // fill weight table: 512 entries, 4 per thread
#pragma unroll
        for (int k = 0; k < 4; ++k) {
            const int e  = t * 4 + k;       // entry
            const int r  = e >> 3;          // row within segment
            const int i  = e & 7;           // group slot
            const int row = mins + seg0 + r;
            wtab[r][i] = (row >= jsL[i] && row < jeL[i]) ? jwL[i] : 0.f;
        }
        __syncthreads();

        const int rend = min(SEG, nrows - seg0);
        const float4* p = base + (size_t)seg0 * (D_DIM / 4);
        for (int r = 0; r < rend; ++r) {
            const float4 v = *p;
            p += (D_DIM / 4);
            const float4 wa = *reinterpret_cast<const float4*>(&wtab[r][0]);
            const float4 wb = *reinterpret_cast<const float4*>(&wtab[r][4]);
            acc[0].x += v.x * wa.x; acc[0].y += v.y * wa.x;
            acc[0].z += v.z * wa.x; acc[0].w += v.w * wa.x;
            acc[1].x += v.x * wa.y; acc[1].y += v.y * wa.y;
            acc[1].z += v.z * wa.y; acc[1].w += v.w * wa.y;
            acc[2].x += v.x * wa.z; acc[2].y += v.y * wa.z;
            acc[2].z += v.z * wa.z; acc[2].w += v.w * wa.z;
            acc[3].x += v.x * wa.w; acc[3].y += v.y * wa.w;
            acc[3].z += v.z * wa.w; acc[3].w += v.w * wa.w;
            acc[4].x += v.x * wb.x; acc[4].y += v.y * wb.x;
            acc[4].z += v.z * wb.x; acc[4].w += v.w * wb.x;
            acc[5].x += v.x * wb.y; acc[5].y += v.y * wb.y;
            acc[5].z += v.z * wb.y; acc[5].w += v.w * wb.y;
            acc[6].x += v.x * wb.z; acc[6].y += v.y * wb.z;
            acc[6].z += v.z * wb.z; acc[6].w += v.w * wb.z;
            acc[7].x += v.x * wb.w; acc[7].y += v.y * wb.w;
            acc[7].z += v.z * wb.w; acc[7].w += v.w * wb.w;
        }
    }

#pragma unroll
    for (int i = 0; i < GROUP; ++i) {
        float* dst = out + (size_t)jp[i] * OUT_STRIDE + jh[i] * D_DIM +
                     ch * 512 + t * 4;
        *reinterpret_cast<float4*>(dst) = acc[i];
        if (ch == 0 && jh[i] == 0 && t < 4) {   // rel row once per pair
            const float4 rv = *reinterpret_cast<const float4*>(
                rtab + ridx[jp[i]] * R_DIM + t * 4);
            *reinterpret_cast<float4*>(
                out + (size_t)jp[i] * OUT_STRIDE + 2 * D_DIM + t * 4) = rv;
        }
    }
}

// ---------------------------------------------------------------------------
extern "C" void kernel_launch(void* const* d_in, const int* in_sizes, int n_in,
                              void* d_out, int out_size, void* d_ws, size_t ws_size,
                              hipStream_t stream) {
    const float* tok  = (const float*)d_in[0];
    const int*   bidx = (const int*)d_in[1];
    const int*   e1s  = (const int*)d_in[2];
    const int*   e1e  = (const int*)d_in[3];
    const int*   e2s  = (const int*)d_in[4];
    const int*   e2e  = (const int*)d_in[5];
    const int*   ridx = (const int*)d_in[6];
    const float* rtab = (const float*)d_in[7];
    float*       out  = (float*)d_out;

    const int P     = in_sizes[1];   // 8192
    const int njobs = 2 * P;         // 16384

    int* cursor = (int*)d_ws;                       // NKEYS ints
    int* sorted = (int*)d_ws + NKEYS;               // njobs ints

    zero_hist<<<NKEYS / 256, 256, 0, stream>>>(cursor);
    hist_jobs<<<(njobs + 255) / 256, 256, 0, stream>>>(bidx, e1s, e2s, cursor, njobs);
    scan_hist<<<1, 1024, 0, stream>>>(cursor);
    scatter_jobs<<<(njobs + 255) / 256, 256, 0, stream>>>(bidx, e1s, e2s, cursor,
                                                          sorted, njobs);
    const int nblocks = (njobs / GROUP) * 2;        // 2 col-slices per group
    gather_grouped4<<<nblocks, 128, 0, stream>>>(
        tok, sorted, bidx, e1s, e1e, e2s, e2e, ridx, rtab, out);
}